// Round 1
// baseline (429.884 us; speedup 1.0000x reference)
//
#include <hip/hip_runtime.h>
#include <stdint.h>

typedef __bf16 bf16;
typedef __bf16 bf16x4 __attribute__((ext_vector_type(4)));
typedef __bf16 bf16x8 __attribute__((ext_vector_type(8)));
typedef float  f32x4  __attribute__((ext_vector_type(4)));

#define DEVI __device__ __forceinline__

DEVI void gll16(const void* g, void* l) {
  __builtin_amdgcn_global_load_lds(
      (const __attribute__((address_space(1))) void*)g,
      (__attribute__((address_space(3))) void*)l,
      16, 0, 0);
}

DEVI f32x4 mfma16(bf16x8 a, bf16x8 b, f32x4 c) {
  return __builtin_amdgcn_mfma_f32_16x16x32_bf16(a, b, c, 0, 0, 0);
}

// ---------------- elementwise ----------------
__global__ void k_copy_f32(const float* __restrict__ in, float* __restrict__ out, int n4) {
  int i = blockIdx.x * 256 + threadIdx.x;
  if (i < n4) ((f32x4*)out)[i] = ((const f32x4*)in)[i];
}

__global__ void k_conv_bf16(const float* __restrict__ in, bf16* __restrict__ out, int n4) {
  int i = blockIdx.x * 256 + threadIdx.x;
  if (i < n4) {
    f32x4 v = ((const f32x4*)in)[i];
    bf16x4 o;
    o[0] = (bf16)v[0]; o[1] = (bf16)v[1]; o[2] = (bf16)v[2]; o[3] = (bf16)v[3];
    ((bf16x4*)out)[i] = o;
  }
}

__global__ void k_concat2(const float* __restrict__ a, const float* __restrict__ b,
                          float* __restrict__ out, int n) {
  int i = blockIdx.x * 256 + threadIdx.x;
  if (i < n) out[i] = a[i];
  else if (i < 2 * n) out[i] = b[i - n];
}

// ------------- weight fp32 [K][N] -> bf16 W^T [N][K] -------------
__global__ void k_wt(const float* __restrict__ W, bf16* __restrict__ WT, int K, int N) {
  __shared__ float t[32][33];
  int bn = blockIdx.x * 32, bk = blockIdx.y * 32;
  int tx = threadIdx.x, ty = threadIdx.y;
#pragma unroll
  for (int i = 0; i < 4; ++i)
    t[ty + i * 8][tx] = W[(size_t)(bk + ty + i * 8) * N + bn + tx];
  __syncthreads();
#pragma unroll
  for (int i = 0; i < 4; ++i)
    WT[(size_t)(bn + ty + i * 8) * K + bk + tx] = (bf16)t[tx][ty + i * 8];
}

// ---------------- layernorm (C=1024) fp32 -> bf16 ----------------
__global__ __launch_bounds__(256)
void k_ln(const float* __restrict__ x, const float* __restrict__ g,
          const float* __restrict__ b, bf16* __restrict__ out) {
  int row = blockIdx.x, tid = threadIdx.x;
  f32x4 v = ((const f32x4*)(x + (size_t)row * 1024))[tid];
  float s = v[0] + v[1] + v[2] + v[3];
  float sq = v[0]*v[0] + v[1]*v[1] + v[2]*v[2] + v[3]*v[3];
#pragma unroll
  for (int m = 1; m < 64; m <<= 1) {
    s  += __shfl_xor(s, m, 64);
    sq += __shfl_xor(sq, m, 64);
  }
  __shared__ float ps[4], psq[4];
  int w = tid >> 6;
  if ((tid & 63) == 0) { ps[w] = s; psq[w] = sq; }
  __syncthreads();
  s  = ps[0] + ps[1] + ps[2] + ps[3];
  sq = psq[0] + psq[1] + psq[2] + psq[3];
  float mean = s * (1.f / 1024.f);
  float rs = rsqrtf(sq * (1.f / 1024.f) - mean * mean + 1e-5f);
  f32x4 gv = ((const f32x4*)g)[tid];
  f32x4 bv = ((const f32x4*)b)[tid];
  bf16x4 o;
#pragma unroll
  for (int i = 0; i < 4; ++i) o[i] = (bf16)((v[i] - mean) * rs * gv[i] + bv[i]);
  ((bf16x4*)(out + (size_t)row * 1024))[tid] = o;
}

// ---------------- GEMM: C[M][N] = A[M][K](bf16) * W^T[N][K](bf16) + bias ----------------
// EPI 0: bf16 out.  EPI 1: fp32 out[idx] += v (residual accumulate in-place).  EPI 2: gelu->bf16.
template <int EPI>
__global__ __launch_bounds__(256, 2)
void k_gemm(const bf16* __restrict__ A, const bf16* __restrict__ BT,
            const float* __restrict__ bias, void* __restrict__ Cout,
            int M, int N, int K) {
  __shared__ __align__(16) char lds[2][2][8192];  // [buf][A/B][128 rows x 64B]
  const int tid = threadIdx.x;
  const int lane = tid & 63;
  const int w = tid >> 6;
  const int lr = lane & 15, lg = lane >> 4;
  const int m0 = blockIdx.y * 128, n0 = blockIdx.x * 128;
  const int wm = (w >> 1) * 64, wn = (w & 1) * 64;
  const int nk = K >> 5;
  const char* Ab = (const char*)A;
  const char* Bb = (const char*)BT;
  const size_t K2 = (size_t)K * 2;

  auto stage = [&](int buf, int kt) {
#pragma unroll
    for (int t = 0; t < 2; ++t) {
      int r = t * 64 + (tid >> 2);
      int cb = (tid & 3) * 16;
      gll16(Ab + (size_t)(m0 + r) * K2 + (size_t)kt * 64 + cb,
            &lds[buf][0][t * 4096 + tid * 16]);
      gll16(Bb + (size_t)(n0 + r) * K2 + (size_t)kt * 64 + cb,
            &lds[buf][1][t * 4096 + tid * 16]);
    }
  };

  f32x4 acc[4][4] = {};

  stage(0, 0);
  __syncthreads();
  int cur = 0;
  for (int kt = 0; kt < nk; ++kt) {
    if (kt + 1 < nk) stage(cur ^ 1, kt + 1);
    bf16x8 af[4], bfr[4];
#pragma unroll
    for (int i = 0; i < 4; ++i) {
      af[i]  = *(const bf16x8*)&lds[cur][0][(wm + i * 16 + lr) * 64 + lg * 16];
      bfr[i] = *(const bf16x8*)&lds[cur][1][(wn + i * 16 + lr) * 64 + lg * 16];
    }
#pragma unroll
    for (int i = 0; i < 4; ++i)
#pragma unroll
      for (int j = 0; j < 4; ++j)
        acc[i][j] = mfma16(af[i], bfr[j], acc[i][j]);
    __syncthreads();
    cur ^= 1;
  }

  float* of = (float*)Cout;
  bf16*  ob = (bf16*)Cout;
#pragma unroll
  for (int j = 0; j < 4; ++j) {
    int gn = n0 + wn + j * 16 + lr;
    float bv = bias[gn];
#pragma unroll
    for (int i = 0; i < 4; ++i) {
#pragma unroll
      for (int r = 0; r < 4; ++r) {
        int gm = m0 + wm + i * 16 + lg * 4 + r;
        size_t idx = (size_t)gm * N + gn;
        float v = acc[i][j][r] + bv;
        if (EPI == 0) ob[idx] = (bf16)v;
        else if (EPI == 1) of[idx] += v;
        else {
          float ge = 0.5f * v * (1.f + erff(v * 0.70710678f));
          ob[idx] = (bf16)ge;
        }
      }
    }
  }
}

// ---------------- fused flash attention (D=64, H=16) ----------------
// Swapped QK^T: S^T = mfma(K, Q) so each lane owns one q column. Online softmax fp32.
template <bool CAUSAL>
__global__ __launch_bounds__(256)
void k_attn(const bf16* __restrict__ Qb, int ldq, int qcol0,
            const bf16* __restrict__ Kb, int kcol0,
            const bf16* __restrict__ Vb, int vcol0,
            int ldkv, int qlen, int kvlen,
            bf16* __restrict__ Ob, int ldo, float scale) {
  const int tid = threadIdx.x;
  const int lane = tid & 63;
  const int w = tid >> 6;
  const int lr = lane & 15, lg = lane >> 4;
  const int h = blockIdx.y;
  const int qt = blockIdx.x;
  const int qrow0 = blockIdx.z * qlen + qt * 64 + w * 16;
  const int qglob = qt * 64 + w * 16 + lr;   // this lane's q column (seq index)
  const int kvbase = blockIdx.z * kvlen;

  // Q fragments (Y operand): lane holds Q[q=lr][kk*32 + lg*8 + j]
  bf16x8 qf[2];
#pragma unroll
  for (int kk = 0; kk < 2; ++kk)
    qf[kk] = *(const bf16x8*)(Qb + (size_t)(qrow0 + lr) * ldq + qcol0 + h * 64 + kk * 32 + lg * 8);

  __shared__ __align__(16) char Klds[8192];   // 64 rows x 128B, XOR-swizzled
  __shared__ __align__(16) bf16 VT[64][68];   // V^T [d][kv], padded

  f32x4 o[4] = {};
  float mrun = -3.0e38f, lsum = 0.f;

  const int nkv = CAUSAL ? (qt + 1) : (kvlen >> 6);

  for (int kvt = 0; kvt < nkv; ++kvt) {
    __syncthreads();  // previous tile's reads done before restaging
    // stage K (swizzled source -> linear LDS via global_load_lds)
#pragma unroll
    for (int t = 0; t < 2; ++t) {
      int r = t * 32 + (tid >> 3);
      int pb = (tid & 7) * 16;
      const char* gs = (const char*)(Kb + (size_t)(kvbase + kvt * 64 + r) * ldkv + kcol0 + h * 64)
                       + (pb ^ ((r & 7) << 4));
      gll16(gs, &Klds[t * 4096 + tid * 16]);
    }
    // stage V transposed: lane = kv (conflict-free writes)
    {
      int kv = tid & 63;
      int d0 = (tid >> 6) * 16;
      const bf16* vp = Vb + (size_t)(kvbase + kvt * 64 + kv) * ldkv + vcol0 + h * 64 + d0;
      bf16x8 v0 = *(const bf16x8*)vp;
      bf16x8 v1 = *(const bf16x8*)(vp + 8);
#pragma unroll
      for (int i = 0; i < 8; ++i) VT[d0 + i][kv] = v0[i];
#pragma unroll
      for (int i = 0; i < 8; ++i) VT[d0 + 8 + i][kv] = v1[i];
    }
    __syncthreads();  // staging visible

    // QK^T (swapped): s[sub] = S^T, lane holds q=lr, kv = sub*16 + lg*4 + j
    f32x4 s[4] = {};
#pragma unroll
    for (int sub = 0; sub < 4; ++sub) {
#pragma unroll
      for (int kk = 0; kk < 2; ++kk) {
        int row = sub * 16 + lr;
        int off = (row << 7) + ((kk * 64 + lg * 16) ^ ((row & 7) << 4));
        bf16x8 kf = *(const bf16x8*)&Klds[off];
        s[sub] = mfma16(kf, qf[kk], s[sub]);
      }
    }
    // scale + causal mask + per-lane max
    float pmax = -3.0e38f;
#pragma unroll
    for (int sub = 0; sub < 4; ++sub)
#pragma unroll
      for (int j = 0; j < 4; ++j) {
        float v = s[sub][j] * scale;
        if (CAUSAL) {
          int kvg = kvt * 64 + sub * 16 + lg * 4 + j;
          if (kvg > qglob) v = -3.0e38f;
        }
        s[sub][j] = v;
        pmax = fmaxf(pmax, v);
      }
    pmax = fmaxf(pmax, __shfl_xor(pmax, 16, 64));
    pmax = fmaxf(pmax, __shfl_xor(pmax, 32, 64));
    float mnew = fmaxf(mrun, pmax);
    float alpha = __expf(mrun - mnew);
    float psum = 0.f;
#pragma unroll
    for (int sub = 0; sub < 4; ++sub)
#pragma unroll
      for (int j = 0; j < 4; ++j) {
        float p = __expf(s[sub][j] - mnew);
        s[sub][j] = p;
        psum += p;
      }
    psum += __shfl_xor(psum, 16, 64);
    psum += __shfl_xor(psum, 32, 64);
    lsum = lsum * alpha + psum;
    mrun = mnew;
    // broadcast alpha to O's q layout (q = lg*4 + j)
    float al[4];
#pragma unroll
    for (int j = 0; j < 4; ++j) {
      int src = (lane & 48) | (lg * 4 + j);
      al[j] = __int_as_float(__builtin_amdgcn_ds_bpermute(src << 2, __float_as_int(alpha)));
    }
#pragma unroll
    for (int dt = 0; dt < 4; ++dt)
#pragma unroll
      for (int j = 0; j < 4; ++j) o[dt][j] *= al[j];
    // PV: o[dt] += P(q=lr, kv-slots) x V(kv, d)
#pragma unroll
    for (int sp = 0; sp < 2; ++sp) {
      bf16x8 pa;
#pragma unroll
      for (int j = 0; j < 4; ++j) {
        pa[j]     = (bf16)s[2 * sp][j];
        pa[4 + j] = (bf16)s[2 * sp + 1][j];
      }
#pragma unroll
      for (int dt = 0; dt < 4; ++dt) {
        int d = dt * 16 + lr;
        bf16x4 va  = *(const bf16x4*)&VT[d][sp * 32 + lg * 4];
        bf16x4 vb2 = *(const bf16x4*)&VT[d][sp * 32 + 16 + lg * 4];
        bf16x8 vf = __builtin_shufflevector(va, vb2, 0, 1, 2, 3, 4, 5, 6, 7);
        o[dt] = mfma16(pa, vf, o[dt]);
      }
    }
  }

  // finalize: divide by lsum (broadcast to q = lg*4 + j), store bf16
  float il[4];
#pragma unroll
  for (int j = 0; j < 4; ++j) {
    int src = (lane & 48) | (lg * 4 + j);
    float ls = __int_as_float(__builtin_amdgcn_ds_bpermute(src << 2, __float_as_int(lsum)));
    il[j] = 1.0f / ls;
  }
#pragma unroll
  for (int dt = 0; dt < 4; ++dt)
#pragma unroll
    for (int j = 0; j < 4; ++j) {
      int gq = qrow0 + lg * 4 + j;
      Ob[(size_t)gq * ldo + h * 64 + dt * 16 + lr] = (bf16)(o[dt][j] * il[j]);
    }
}

// ---------------- host orchestration ----------------
extern "C" void kernel_launch(void* const* d_in, const int* in_sizes, int n_in,
                              void* d_out, int out_size, void* d_ws, size_t ws_size,
                              hipStream_t stream) {
  (void)in_sizes; (void)n_in; (void)out_size; (void)ws_size;
  const float* x        = (const float*)d_in[0];
  const float* plan     = (const float*)d_in[1];
  const float* ln1_g    = (const float*)d_in[2];
  const float* ln1_b    = (const float*)d_in[3];
  const float* c_attn_w = (const float*)d_in[4];
  const float* c_attn_b = (const float*)d_in[5];
  const float* aproj_w  = (const float*)d_in[6];
  const float* aproj_b  = (const float*)d_in[7];
  const float* ln2_g    = (const float*)d_in[8];
  const float* ln2_b    = (const float*)d_in[9];
  const float* q_w      = (const float*)d_in[10];
  const float* q_b      = (const float*)d_in[11];
  const float* k_w      = (const float*)d_in[12];
  const float* k_b      = (const float*)d_in[13];
  const float* v_w      = (const float*)d_in[14];
  const float* v_b      = (const float*)d_in[15];
  const float* ca_w     = (const float*)d_in[16];
  const float* ca_b     = (const float*)d_in[17];
  const float* ln3_g    = (const float*)d_in[18];
  const float* ln3_b    = (const float*)d_in[19];
  const float* fc_w     = (const float*)d_in[20];
  const float* fc_b     = (const float*)d_in[21];
  const float* mp_w     = (const float*)d_in[22];
  const float* mp_b     = (const float*)d_in[23];

  char* ws = (char*)d_ws;
  bf16*  wbuf   = (bf16*)(ws);                        // 8 MiB rotating W^T
  bf16*  lnb    = (bf16*)(ws + (8ull << 20));         // 8 MiB LN output
  bf16*  planb  = (bf16*)(ws + (16ull << 20));        // 2 MiB plan bf16
  bf16*  yb     = (bf16*)(ws + (18ull << 20));        // 8 MiB attn output
  char*  rega   = ws + (26ull << 20);                 // 32 MiB region (qkv | qx+kv | hmid)
  float* biaskv = (float*)(ws + (58ull << 20));       // 8 KiB
  bf16* qkv  = (bf16*)rega;
  bf16* qx   = (bf16*)rega;
  bf16* kvc  = (bf16*)(rega + (8ull << 20));
  bf16* hmid = (bf16*)rega;
  float* xw = (float*)d_out;   // running residual stream (fp32)

  dim3 wtb(32, 8);

  k_copy_f32<<<4096, 256, 0, stream>>>(x, xw, 1048576);
  k_conv_bf16<<<1024, 256, 0, stream>>>(plan, planb, 262144);
  k_concat2<<<8, 256, 0, stream>>>(k_b, v_b, biaskv, 1024);

  // ----- self-attention -----
  k_ln<<<4096, 256, 0, stream>>>(xw, ln1_g, ln1_b, lnb);
  k_wt<<<dim3(96, 32), wtb, 0, stream>>>(c_attn_w, wbuf, 1024, 3072);
  k_gemm<0><<<dim3(24, 32), 256, 0, stream>>>(lnb, wbuf, c_attn_b, qkv, 4096, 3072, 1024);
  k_attn<true><<<dim3(32, 16, 2), 256, 0, stream>>>(qkv, 3072, 0, qkv, 1024, qkv, 2048,
                                                    3072, 2048, 2048, yb, 1024, 0.125f);
  k_wt<<<dim3(32, 32), wtb, 0, stream>>>(aproj_w, wbuf, 1024, 1024);
  k_gemm<1><<<dim3(8, 32), 256, 0, stream>>>(yb, wbuf, aproj_b, xw, 4096, 1024, 1024);

  // ----- cross-attention -----
  k_ln<<<4096, 256, 0, stream>>>(xw, ln2_g, ln2_b, lnb);
  k_wt<<<dim3(32, 32), wtb, 0, stream>>>(q_w, wbuf, 1024, 1024);
  k_gemm<0><<<dim3(8, 32), 256, 0, stream>>>(lnb, wbuf, q_b, qx, 4096, 1024, 1024);
  k_wt<<<dim3(32, 32), wtb, 0, stream>>>(k_w, wbuf, 1024, 1024);
  k_wt<<<dim3(32, 32), wtb, 0, stream>>>(v_w, wbuf + 1024 * 1024, 1024, 1024);
  k_gemm<0><<<dim3(16, 8), 256, 0, stream>>>(planb, wbuf, biaskv, kvc, 1024, 2048, 1024);
  k_attn<false><<<dim3(32, 16, 2), 256, 0, stream>>>(qx, 1024, 0, kvc, 0, kvc, 1024,
                                                     2048, 2048, 512, yb, 1024, 0.125f);
  k_wt<<<dim3(32, 32), wtb, 0, stream>>>(ca_w, wbuf, 1024, 1024);
  k_gemm<1><<<dim3(8, 32), 256, 0, stream>>>(yb, wbuf, ca_b, xw, 4096, 1024, 1024);

  // ----- MLP -----
  k_ln<<<4096, 256, 0, stream>>>(xw, ln3_g, ln3_b, lnb);
  k_wt<<<dim3(128, 32), wtb, 0, stream>>>(fc_w, wbuf, 1024, 4096);
  k_gemm<2><<<dim3(32, 32), 256, 0, stream>>>(lnb, wbuf, fc_b, hmid, 4096, 4096, 1024);
  k_wt<<<dim3(32, 128), wtb, 0, stream>>>(mp_w, wbuf, 4096, 1024);
  k_gemm<1><<<dim3(8, 32), 256, 0, stream>>>(hmid, wbuf, mp_b, xw, 4096, 1024, 4096);
}

// Round 2
// 407.072 us; speedup vs baseline: 1.0560x; 1.0560x over previous
//
#include <hip/hip_runtime.h>
#include <stdint.h>

typedef __bf16 bf16;
typedef __bf16 bf16x4 __attribute__((ext_vector_type(4)));
typedef __bf16 bf16x8 __attribute__((ext_vector_type(8)));
typedef float  f32x4  __attribute__((ext_vector_type(4)));

#define DEVI __device__ __forceinline__

DEVI void gll16(const void* g, void* l) {
  __builtin_amdgcn_global_load_lds(
      (const __attribute__((address_space(1))) void*)g,
      (__attribute__((address_space(3))) void*)l,
      16, 0, 0);
}

DEVI f32x4 mfma16(bf16x8 a, bf16x8 b, f32x4 c) {
  return __builtin_amdgcn_mfma_f32_16x16x32_bf16(a, b, c, 0, 0, 0);
}

// ---------------- elementwise ----------------
__global__ void k_copy_f32(const float* __restrict__ in, float* __restrict__ out, int n4) {
  int i = blockIdx.x * 256 + threadIdx.x;
  if (i < n4) ((f32x4*)out)[i] = ((const f32x4*)in)[i];
}

__global__ void k_conv_bf16(const float* __restrict__ in, bf16* __restrict__ out, int n4) {
  int i = blockIdx.x * 256 + threadIdx.x;
  if (i < n4) {
    f32x4 v = ((const f32x4*)in)[i];
    bf16x4 o;
    o[0] = (bf16)v[0]; o[1] = (bf16)v[1]; o[2] = (bf16)v[2]; o[3] = (bf16)v[3];
    ((bf16x4*)out)[i] = o;
  }
}

__global__ void k_concat2(const float* __restrict__ a, const float* __restrict__ b,
                          float* __restrict__ out, int n) {
  int i = blockIdx.x * 256 + threadIdx.x;
  if (i < n) out[i] = a[i];
  else if (i < 2 * n) out[i] = b[i - n];
}

// ------------- weight fp32 [K][N] -> bf16 W^T [N][K] -------------
__global__ void k_wt(const float* __restrict__ W, bf16* __restrict__ WT, int K, int N) {
  __shared__ float t[32][33];
  int bn = blockIdx.x * 32, bk = blockIdx.y * 32;
  int tx = threadIdx.x, ty = threadIdx.y;
#pragma unroll
  for (int i = 0; i < 4; ++i)
    t[ty + i * 8][tx] = W[(size_t)(bk + ty + i * 8) * N + bn + tx];
  __syncthreads();
#pragma unroll
  for (int i = 0; i < 4; ++i)
    WT[(size_t)(bn + ty + i * 8) * K + bk + tx] = (bf16)t[tx][ty + i * 8];
}

// ---------------- layernorm (C=1024) fp32 -> bf16 ----------------
__global__ __launch_bounds__(256)
void k_ln(const float* __restrict__ x, const float* __restrict__ g,
          const float* __restrict__ b, bf16* __restrict__ out) {
  int row = blockIdx.x, tid = threadIdx.x;
  f32x4 v = ((const f32x4*)(x + (size_t)row * 1024))[tid];
  float s = v[0] + v[1] + v[2] + v[3];
  float sq = v[0]*v[0] + v[1]*v[1] + v[2]*v[2] + v[3]*v[3];
#pragma unroll
  for (int m = 1; m < 64; m <<= 1) {
    s  += __shfl_xor(s, m, 64);
    sq += __shfl_xor(sq, m, 64);
  }
  __shared__ float ps[4], psq[4];
  int w = tid >> 6;
  if ((tid & 63) == 0) { ps[w] = s; psq[w] = sq; }
  __syncthreads();
  s  = ps[0] + ps[1] + ps[2] + ps[3];
  sq = psq[0] + psq[1] + psq[2] + psq[3];
  float mean = s * (1.f / 1024.f);
  float rs = rsqrtf(sq * (1.f / 1024.f) - mean * mean + 1e-5f);
  f32x4 gv = ((const f32x4*)g)[tid];
  f32x4 bv = ((const f32x4*)b)[tid];
  bf16x4 o;
#pragma unroll
  for (int i = 0; i < 4; ++i) o[i] = (bf16)((v[i] - mean) * rs * gv[i] + bv[i]);
  ((bf16x4*)(out + (size_t)row * 1024))[tid] = o;
}

// ---------------- GEMM: C[M][N] = A[M][K](bf16) * W^T[N][K](bf16) + bias ----------------
// EPI 0: bf16 out.  EPI 1: fp32 out[idx] += v.  EPI 2: gelu->bf16.
template <int EPI>
__global__ __launch_bounds__(256, 2)
void k_gemm(const bf16* __restrict__ A, const bf16* __restrict__ BT,
            const float* __restrict__ bias, void* __restrict__ Cout,
            int M, int N, int K) {
  __shared__ __align__(16) char lds[2][2][8192];
  const int tid = threadIdx.x;
  const int lane = tid & 63;
  const int w = tid >> 6;
  const int lr = lane & 15, lg = lane >> 4;
  const int m0 = blockIdx.y * 128, n0 = blockIdx.x * 128;
  const int wm = (w >> 1) * 64, wn = (w & 1) * 64;
  const int nk = K >> 5;
  const char* Ab = (const char*)A;
  const char* Bb = (const char*)BT;
  const size_t K2 = (size_t)K * 2;

  auto stage = [&](int buf, int kt) {
#pragma unroll
    for (int t = 0; t < 2; ++t) {
      int r = t * 64 + (tid >> 2);
      int cb = (tid & 3) * 16;
      gll16(Ab + (size_t)(m0 + r) * K2 + (size_t)kt * 64 + cb,
            &lds[buf][0][t * 4096 + tid * 16]);
      gll16(Bb + (size_t)(n0 + r) * K2 + (size_t)kt * 64 + cb,
            &lds[buf][1][t * 4096 + tid * 16]);
    }
  };

  f32x4 acc[4][4] = {};

  stage(0, 0);
  __syncthreads();
  int cur = 0;
  for (int kt = 0; kt < nk; ++kt) {
    if (kt + 1 < nk) stage(cur ^ 1, kt + 1);
    bf16x8 af[4], bfr[4];
#pragma unroll
    for (int i = 0; i < 4; ++i) {
      af[i]  = *(const bf16x8*)&lds[cur][0][(wm + i * 16 + lr) * 64 + lg * 16];
      bfr[i] = *(const bf16x8*)&lds[cur][1][(wn + i * 16 + lr) * 64 + lg * 16];
    }
#pragma unroll
    for (int i = 0; i < 4; ++i)
#pragma unroll
      for (int j = 0; j < 4; ++j)
        acc[i][j] = mfma16(af[i], bfr[j], acc[i][j]);
    __syncthreads();
    cur ^= 1;
  }

  float* of = (float*)Cout;
  bf16*  ob = (bf16*)Cout;
#pragma unroll
  for (int j = 0; j < 4; ++j) {
    int gn = n0 + wn + j * 16 + lr;
    float bv = bias[gn];
#pragma unroll
    for (int i = 0; i < 4; ++i) {
#pragma unroll
      for (int r = 0; r < 4; ++r) {
        int gm = m0 + wm + i * 16 + lg * 4 + r;
        size_t idx = (size_t)gm * N + gn;
        float v = acc[i][j][r] + bv;
        if (EPI == 0) ob[idx] = (bf16)v;
        else if (EPI == 1) of[idx] += v;
        else {
          float ge = 0.5f * v * (1.f + erff(v * 0.70710678f));
          ob[idx] = (bf16)ge;
        }
      }
    }
  }
}

// ---------------- fused flash attention v2 (D=64, H=16) ----------------
// QBLK=128 (4 waves x 32 q), KVBLK=64, double-buffered K(gll16)+V(reg-staged),
// one barrier per tile (T14 async-STAGE split), defer-max (T13, THR=8).
// Swapped QK^T: lane owns q=lane&15 per 16-q group; softmax fully lane-local.
template <bool CAUSAL>
__global__ __launch_bounds__(256)
void k_attn2(const bf16* __restrict__ Qb, int ldq, int qcol0,
             const bf16* __restrict__ Kb, int kcol0,
             const bf16* __restrict__ Vb, int vcol0,
             int ldkv, int qlen, int kvlen,
             bf16* __restrict__ Ob, int ldo, float scale) {
  const int tid = threadIdx.x;
  const int lane = tid & 63;
  const int w = tid >> 6;
  const int lr = lane & 15, lg = lane >> 4;

  // block decode; for CAUSAL pair heavy qt with light qt so co-resident blocks balance
  int id = blockIdx.x;
  int h, b, qt;
  if (CAUSAL) {
    int low = id & 255;
    h = low & 15; b = (low >> 4) & 1;
    int q3 = low >> 5;                      // 0..7
    qt = (id >> 8) ? (8 + q3) : (7 - q3);   // halves sum to 15
  } else {
    h = id & 15; b = (id >> 4) & 1; qt = id >> 5;
  }

  const int qbase = qt * 128;
  const int kvbase = b * kvlen;
  const int nkv = CAUSAL ? (2 * qt + 2) : (kvlen >> 6);
  const int mask_from = CAUSAL ? (nkv - 2) : 0x7fffffff;

  // Q fragments: qf[g][kk] = Q[q = qbase + w*32 + g*16 + lr][kk*32 + lg*8 ..+8]
  bf16x8 qf[2][2];
#pragma unroll
  for (int g = 0; g < 2; ++g)
#pragma unroll
    for (int kk = 0; kk < 2; ++kk)
      qf[g][kk] = *(const bf16x8*)(Qb + (size_t)(b * qlen + qbase + w * 32 + g * 16 + lr) * ldq
                                   + qcol0 + h * 64 + kk * 32 + lg * 8);

  __shared__ __align__(16) char Klds[2][8192];   // 64 rows x 128B, XOR-swizzled image
  __shared__ __align__(16) bf16 VT[2][64][68];   // V^T [d][kv], padded (conflict-free)

  f32x4 o[2][4] = {};
  float mrun[2] = {-3.0e38f, -3.0e38f};
  float lsum[2] = {0.f, 0.f};

  // V staging registers (next tile)
  bf16x8 vr0, vr1;
  const int vkv = lane;
  const int vd0 = (tid >> 6) * 16;
  const bf16* Vbase = Vb + vcol0 + h * 64 + vd0;

  auto stageK = [&](int buf, int kvt) {
#pragma unroll
    for (int t = 0; t < 2; ++t) {
      int r = t * 32 + (tid >> 3);
      int pb = (tid & 7) * 16;
      const char* gs = (const char*)(Kb + (size_t)(kvbase + kvt * 64 + r) * ldkv + kcol0 + h * 64)
                       + (pb ^ ((r & 7) << 4));
      gll16(gs, &Klds[buf][t * 4096 + tid * 16]);
    }
  };
  auto loadV = [&](int kvt) {
    const bf16* vp = Vbase + (size_t)(kvbase + kvt * 64 + vkv) * ldkv;
    vr0 = *(const bf16x8*)vp;
    vr1 = *(const bf16x8*)(vp + 8);
  };
  auto writeV = [&](int buf) {
#pragma unroll
    for (int i = 0; i < 8; ++i) VT[buf][vd0 + i][vkv] = vr0[i];
#pragma unroll
    for (int i = 0; i < 8; ++i) VT[buf][vd0 + 8 + i][vkv] = vr1[i];
  };

  // prologue: tile 0 fully staged
  stageK(0, 0);
  loadV(0);
  writeV(0);
  __syncthreads();   // drains vmcnt (gll16) + ds writes visible

  int cur = 0;
  for (int kvt = 0; kvt < nkv; ++kvt) {
    // issue next tile's loads before compute (latency hides under QK/softmax/PV)
    if (kvt + 1 < nkv) { stageK(cur ^ 1, kvt + 1); loadV(kvt + 1); }

    // QK^T for both q-groups, sharing K fragments
    f32x4 s[2][4] = {};
#pragma unroll
    for (int sub = 0; sub < 4; ++sub) {
      int row = sub * 16 + lr;
#pragma unroll
      for (int kk = 0; kk < 2; ++kk) {
        bf16x8 kf = *(const bf16x8*)&Klds[cur][(row << 7) + ((kk * 64 + lg * 16) ^ ((row & 7) << 4))];
        s[0][sub] = mfma16(kf, qf[0][kk], s[0][sub]);
        s[1][sub] = mfma16(kf, qf[1][kk], s[1][sub]);
      }
    }

    const bool domask = CAUSAL && (kvt >= mask_from);
    bf16x8 pa[2][2];
#pragma unroll
    for (int g = 0; g < 2; ++g) {
      const int qg = qbase + w * 32 + g * 16 + lr;
      float pmax = -3.0e38f;
#pragma unroll
      for (int sub = 0; sub < 4; ++sub)
#pragma unroll
        for (int j = 0; j < 4; ++j) {
          float v = s[g][sub][j] * scale;
          if (domask) {
            int kvg = kvt * 64 + sub * 16 + lg * 4 + j;
            if (kvg > qg) v = -3.0e38f;
          }
          s[g][sub][j] = v;
          pmax = fmaxf(pmax, v);
        }
      pmax = fmaxf(pmax, __shfl_xor(pmax, 16, 64));
      pmax = fmaxf(pmax, __shfl_xor(pmax, 32, 64));
      float mnew = mrun[g];
      if (__any(pmax - mrun[g] > 8.f)) {       // defer-max: rescale only on real growth
        mnew = fmaxf(mrun[g], pmax);
        float alpha = __expf(mrun[g] - mnew);
        lsum[g] *= alpha;
        float al[4];
#pragma unroll
        for (int j = 0; j < 4; ++j) {
          int src = (lane & 48) | (lg * 4 + j);
          al[j] = __int_as_float(__builtin_amdgcn_ds_bpermute(src << 2, __float_as_int(alpha)));
        }
#pragma unroll
        for (int dt = 0; dt < 4; ++dt)
#pragma unroll
          for (int j = 0; j < 4; ++j) o[g][dt][j] *= al[j];
      }
      float psum = 0.f;
#pragma unroll
      for (int sub = 0; sub < 4; ++sub)
#pragma unroll
        for (int j = 0; j < 4; ++j) {
          float p = __expf(s[g][sub][j] - mnew);
          s[g][sub][j] = p;
          psum += p;
        }
      psum += __shfl_xor(psum, 16, 64);
      psum += __shfl_xor(psum, 32, 64);
      lsum[g] += psum;
      mrun[g] = mnew;
#pragma unroll
      for (int sp = 0; sp < 2; ++sp) {
#pragma unroll
        for (int j = 0; j < 4; ++j) {
          pa[g][sp][j]     = (bf16)s[g][2 * sp][j];
          pa[g][sp][4 + j] = (bf16)s[g][2 * sp + 1][j];
        }
      }
    }

    // PV for both groups, sharing V fragments
#pragma unroll
    for (int sp = 0; sp < 2; ++sp) {
#pragma unroll
      for (int dt = 0; dt < 4; ++dt) {
        int d = dt * 16 + lr;
        bf16x4 va  = *(const bf16x4*)&VT[cur][d][sp * 32 + lg * 4];
        bf16x4 vb2 = *(const bf16x4*)&VT[cur][d][sp * 32 + 16 + lg * 4];
        bf16x8 vf = __builtin_shufflevector(va, vb2, 0, 1, 2, 3, 4, 5, 6, 7);
        o[0][dt] = mfma16(pa[0][sp], vf, o[0][dt]);
        o[1][dt] = mfma16(pa[1][sp], vf, o[1][dt]);
      }
    }

    if (kvt + 1 < nkv) writeV(cur ^ 1);   // V regs landed during compute
    __syncthreads();                       // staging visible; buffers swap safe
    cur ^= 1;
  }

  // finalize
#pragma unroll
  for (int g = 0; g < 2; ++g) {
    float il[4];
#pragma unroll
    for (int j = 0; j < 4; ++j) {
      int src = (lane & 48) | (lg * 4 + j);
      float ls = __int_as_float(__builtin_amdgcn_ds_bpermute(src << 2, __float_as_int(lsum[g])));
      il[j] = 1.0f / ls;
    }
#pragma unroll
    for (int dt = 0; dt < 4; ++dt)
#pragma unroll
      for (int j = 0; j < 4; ++j) {
        int gq = b * qlen + qbase + w * 32 + g * 16 + lg * 4 + j;
        Ob[(size_t)gq * ldo + h * 64 + dt * 16 + lr] = (bf16)(o[g][dt][j] * il[j]);
      }
  }
}

// ---------------- host orchestration ----------------
extern "C" void kernel_launch(void* const* d_in, const int* in_sizes, int n_in,
                              void* d_out, int out_size, void* d_ws, size_t ws_size,
                              hipStream_t stream) {
  (void)in_sizes; (void)n_in; (void)out_size; (void)ws_size;
  const float* x        = (const float*)d_in[0];
  const float* plan     = (const float*)d_in[1];
  const float* ln1_g    = (const float*)d_in[2];
  const float* ln1_b    = (const float*)d_in[3];
  const float* c_attn_w = (const float*)d_in[4];
  const float* c_attn_b = (const float*)d_in[5];
  const float* aproj_w  = (const float*)d_in[6];
  const float* aproj_b  = (const float*)d_in[7];
  const float* ln2_g    = (const float*)d_in[8];
  const float* ln2_b    = (const float*)d_in[9];
  const float* q_w      = (const float*)d_in[10];
  const float* q_b      = (const float*)d_in[11];
  const float* k_w      = (const float*)d_in[12];
  const float* k_b      = (const float*)d_in[13];
  const float* v_w      = (const float*)d_in[14];
  const float* v_b      = (const float*)d_in[15];
  const float* ca_w     = (const float*)d_in[16];
  const float* ca_b     = (const float*)d_in[17];
  const float* ln3_g    = (const float*)d_in[18];
  const float* ln3_b    = (const float*)d_in[19];
  const float* fc_w     = (const float*)d_in[20];
  const float* fc_b     = (const float*)d_in[21];
  const float* mp_w     = (const float*)d_in[22];
  const float* mp_b     = (const float*)d_in[23];

  char* ws = (char*)d_ws;
  bf16*  wbuf   = (bf16*)(ws);                        // 8 MiB rotating W^T
  bf16*  lnb    = (bf16*)(ws + (8ull << 20));         // 8 MiB LN output
  bf16*  planb  = (bf16*)(ws + (16ull << 20));        // 2 MiB plan bf16
  bf16*  yb     = (bf16*)(ws + (18ull << 20));        // 8 MiB attn output
  char*  rega   = ws + (26ull << 20);                 // 32 MiB region (qkv | qx+kv | hmid)
  float* biaskv = (float*)(ws + (58ull << 20));       // 8 KiB
  bf16* qkv  = (bf16*)rega;
  bf16* qx   = (bf16*)rega;
  bf16* kvc  = (bf16*)(rega + (8ull << 20));
  bf16* hmid = (bf16*)rega;
  float* xw = (float*)d_out;   // running residual stream (fp32)

  dim3 wtb(32, 8);

  k_copy_f32<<<4096, 256, 0, stream>>>(x, xw, 1048576);
  k_conv_bf16<<<1024, 256, 0, stream>>>(plan, planb, 262144);
  k_concat2<<<8, 256, 0, stream>>>(k_b, v_b, biaskv, 1024);

  // ----- self-attention -----
  k_ln<<<4096, 256, 0, stream>>>(xw, ln1_g, ln1_b, lnb);
  k_wt<<<dim3(96, 32), wtb, 0, stream>>>(c_attn_w, wbuf, 1024, 3072);
  k_gemm<0><<<dim3(24, 32), 256, 0, stream>>>(lnb, wbuf, c_attn_b, qkv, 4096, 3072, 1024);
  k_attn2<true><<<512, 256, 0, stream>>>(qkv, 3072, 0, qkv, 1024, qkv, 2048,
                                         3072, 2048, 2048, yb, 1024, 0.125f);
  k_wt<<<dim3(32, 32), wtb, 0, stream>>>(aproj_w, wbuf, 1024, 1024);
  k_gemm<1><<<dim3(8, 32), 256, 0, stream>>>(yb, wbuf, aproj_b, xw, 4096, 1024, 1024);

  // ----- cross-attention -----
  k_ln<<<4096, 256, 0, stream>>>(xw, ln2_g, ln2_b, lnb);
  k_wt<<<dim3(32, 32), wtb, 0, stream>>>(q_w, wbuf, 1024, 1024);
  k_gemm<0><<<dim3(8, 32), 256, 0, stream>>>(lnb, wbuf, q_b, qx, 4096, 1024, 1024);
  k_wt<<<dim3(32, 32), wtb, 0, stream>>>(k_w, wbuf, 1024, 1024);
  k_wt<<<dim3(32, 32), wtb, 0, stream>>>(v_w, wbuf + 1024 * 1024, 1024, 1024);
  k_gemm<0><<<dim3(16, 8), 256, 0, stream>>>(planb, wbuf, biaskv, kvc, 1024, 2048, 1024);
  k_attn2<false><<<512, 256, 0, stream>>>(qx, 1024, 0, kvc, 0, kvc, 1024,
                                          2048, 2048, 512, yb, 1024, 0.125f);
  k_wt<<<dim3(32, 32), wtb, 0, stream>>>(ca_w, wbuf, 1024, 1024);
  k_gemm<1><<<dim3(8, 32), 256, 0, stream>>>(yb, wbuf, ca_b, xw, 4096, 1024, 1024);

  // ----- MLP -----
  k_ln<<<4096, 256, 0, stream>>>(xw, ln3_g, ln3_b, lnb);
  k_wt<<<dim3(128, 32), wtb, 0, stream>>>(fc_w, wbuf, 1024, 4096);
  k_gemm<2><<<dim3(32, 32), 256, 0, stream>>>(lnb, wbuf, fc_b, hmid, 4096, 4096, 1024);
  k_wt<<<dim3(32, 128), wtb, 0, stream>>>(mp_w, wbuf, 4096, 1024);
  k_gemm<1><<<dim3(8, 32), 256, 0, stream>>>(hmid, wbuf, mp_b, xw, 4096, 1024, 4096);
}

// Round 3
// 406.864 us; speedup vs baseline: 1.0566x; 1.0005x over previous
//
#include <hip/hip_runtime.h>
#include <stdint.h>

typedef __bf16 bf16;
typedef __bf16 bf16x4 __attribute__((ext_vector_type(4)));
typedef __bf16 bf16x8 __attribute__((ext_vector_type(8)));
typedef float  f32x4  __attribute__((ext_vector_type(4)));

#define DEVI __device__ __forceinline__

DEVI void gll16(const void* g, void* l) {
  __builtin_amdgcn_global_load_lds(
      (const __attribute__((address_space(1))) void*)g,
      (__attribute__((address_space(3))) void*)l,
      16, 0, 0);
}

DEVI f32x4 mfma16(bf16x8 a, bf16x8 b, f32x4 c) {
  return __builtin_amdgcn_mfma_f32_16x16x32_bf16(a, b, c, 0, 0, 0);
}

// ---------------- elementwise ----------------
__global__ void k_copy_f32(const float* __restrict__ in, float* __restrict__ out, int n4) {
  int i = blockIdx.x * 256 + threadIdx.x;
  if (i < n4) ((f32x4*)out)[i] = ((const f32x4*)in)[i];
}

__global__ void k_conv_bf16(const float* __restrict__ in, bf16* __restrict__ out, int n4) {
  int i = blockIdx.x * 256 + threadIdx.x;
  if (i < n4) {
    f32x4 v = ((const f32x4*)in)[i];
    bf16x4 o;
    o[0] = (bf16)v[0]; o[1] = (bf16)v[1]; o[2] = (bf16)v[2]; o[3] = (bf16)v[3];
    ((bf16x4*)out)[i] = o;
  }
}

__global__ void k_concat2(const float* __restrict__ a, const float* __restrict__ b,
                          float* __restrict__ out, int n) {
  int i = blockIdx.x * 256 + threadIdx.x;
  if (i < n) out[i] = a[i];
  else if (i < 2 * n) out[i] = b[i - n];
}

// ------------- weight fp32 [K][N] -> bf16 W^T [N][K] -------------
__global__ void k_wt(const float* __restrict__ W, bf16* __restrict__ WT, int K, int N) {
  __shared__ float t[32][33];
  int bn = blockIdx.x * 32, bk = blockIdx.y * 32;
  int tx = threadIdx.x, ty = threadIdx.y;
#pragma unroll
  for (int i = 0; i < 4; ++i)
    t[ty + i * 8][tx] = W[(size_t)(bk + ty + i * 8) * N + bn + tx];
  __syncthreads();
#pragma unroll
  for (int i = 0; i < 4; ++i)
    WT[(size_t)(bn + ty + i * 8) * K + bk + tx] = (bf16)t[tx][ty + i * 8];
}

// ---------------- layernorm (C=1024) fp32 -> bf16 ----------------
__global__ __launch_bounds__(256)
void k_ln(const float* __restrict__ x, const float* __restrict__ g,
          const float* __restrict__ b, bf16* __restrict__ out) {
  int row = blockIdx.x, tid = threadIdx.x;
  f32x4 v = ((const f32x4*)(x + (size_t)row * 1024))[tid];
  float s = v[0] + v[1] + v[2] + v[3];
  float sq = v[0]*v[0] + v[1]*v[1] + v[2]*v[2] + v[3]*v[3];
#pragma unroll
  for (int m = 1; m < 64; m <<= 1) {
    s  += __shfl_xor(s, m, 64);
    sq += __shfl_xor(sq, m, 64);
  }
  __shared__ float ps[4], psq[4];
  int w = tid >> 6;
  if ((tid & 63) == 0) { ps[w] = s; psq[w] = sq; }
  __syncthreads();
  s  = ps[0] + ps[1] + ps[2] + ps[3];
  sq = psq[0] + psq[1] + psq[2] + psq[3];
  float mean = s * (1.f / 1024.f);
  float rs = rsqrtf(sq * (1.f / 1024.f) - mean * mean + 1e-5f);
  f32x4 gv = ((const f32x4*)g)[tid];
  f32x4 bv = ((const f32x4*)b)[tid];
  bf16x4 o;
#pragma unroll
  for (int i = 0; i < 4; ++i) o[i] = (bf16)((v[i] - mean) * rs * gv[i] + bv[i]);
  ((bf16x4*)(out + (size_t)row * 1024))[tid] = o;
}

// ---------------- GEMM 128x128 (2-phase) — for small-N / small-M shapes ----------------
// EPI 0: bf16 out.  EPI 1: fp32 out[idx] += v.  EPI 2: gelu->bf16.
template <int EPI>
__global__ __launch_bounds__(256, 2)
void k_gemm(const bf16* __restrict__ A, const bf16* __restrict__ BT,
            const float* __restrict__ bias, void* __restrict__ Cout,
            int M, int N, int K) {
  __shared__ __align__(16) char lds[2][2][8192];
  const int tid = threadIdx.x;
  const int lane = tid & 63;
  const int w = tid >> 6;
  const int lr = lane & 15, lg = lane >> 4;
  const int m0 = blockIdx.y * 128, n0 = blockIdx.x * 128;
  const int wm = (w >> 1) * 64, wn = (w & 1) * 64;
  const int nk = K >> 5;
  const char* Ab = (const char*)A;
  const char* Bb = (const char*)BT;
  const size_t K2 = (size_t)K * 2;

  auto stage = [&](int buf, int kt) {
#pragma unroll
    for (int t = 0; t < 2; ++t) {
      int r = t * 64 + (tid >> 2);
      int cb = (tid & 3) * 16;
      gll16(Ab + (size_t)(m0 + r) * K2 + (size_t)kt * 64 + cb,
            &lds[buf][0][t * 4096 + tid * 16]);
      gll16(Bb + (size_t)(n0 + r) * K2 + (size_t)kt * 64 + cb,
            &lds[buf][1][t * 4096 + tid * 16]);
    }
  };

  f32x4 acc[4][4] = {};

  stage(0, 0);
  __syncthreads();
  int cur = 0;
  for (int kt = 0; kt < nk; ++kt) {
    if (kt + 1 < nk) stage(cur ^ 1, kt + 1);
    bf16x8 af[4], bfr[4];
#pragma unroll
    for (int i = 0; i < 4; ++i) {
      af[i]  = *(const bf16x8*)&lds[cur][0][(wm + i * 16 + lr) * 64 + lg * 16];
      bfr[i] = *(const bf16x8*)&lds[cur][1][(wn + i * 16 + lr) * 64 + lg * 16];
    }
#pragma unroll
    for (int i = 0; i < 4; ++i)
#pragma unroll
      for (int j = 0; j < 4; ++j)
        acc[i][j] = mfma16(af[i], bfr[j], acc[i][j]);
    __syncthreads();
    cur ^= 1;
  }

  float* of = (float*)Cout;
  bf16*  ob = (bf16*)Cout;
#pragma unroll
  for (int j = 0; j < 4; ++j) {
    int gn = n0 + wn + j * 16 + lr;
    float bv = bias[gn];
#pragma unroll
    for (int i = 0; i < 4; ++i) {
#pragma unroll
      for (int r = 0; r < 4; ++r) {
        int gm = m0 + wm + i * 16 + lg * 4 + r;
        size_t idx = (size_t)gm * N + gn;
        float v = acc[i][j][r] + bv;
        if (EPI == 0) ob[idx] = (bf16)v;
        else if (EPI == 1) of[idx] += v;
        else {
          float ge = 0.5f * v * (1.f + erff(v * 0.70710678f));
          ob[idx] = (bf16)ge;
        }
      }
    }
  }
}

// ---------------- GEMM 256x256 8-phase counted-vmcnt (T2+T3+T4+T5) ----------------
// 512 thr = 8 waves (2M x 4N, interleaved 16-row stripes). BK=64.
// LDS 128KB: [dbuf][half] 16KB half-tiles for A and B, G4 XOR-swizzled via
// pre-swizzled global source (linear LDS dest for global_load_lds).
// Staging plan per tile t (one half per phase, clamped source at tail):
//   ph0: B1(t+1)  ph1: A1(t+1)  ph2: A0(t+2)  ph3: B0(t+2)
// vmcnt(8) guards each half one phase before its first ds_read (barrier-separated).
template <int EPI>
__global__ __launch_bounds__(512, 2)
void k_gemm8(const bf16* __restrict__ A, const bf16* __restrict__ BT,
             const float* __restrict__ bias, void* __restrict__ Cout,
             int M, int N, int K) {
  __shared__ __align__(16) char SA[2][2][16384];
  __shared__ __align__(16) char SB[2][2][16384];
  const int tid = threadIdx.x;
  const int lane = tid & 63;
  const int w = tid >> 6;
  const int wm = w >> 2, wn = w & 3;
  const int lr = lane & 15, lg = lane >> 4;
  const int nk = K >> 6;

  // bijective XCD swizzle (m204)
  const int nwg = gridDim.x;
  const int q = nwg >> 3, r = nwg & 7;
  const int xcd = blockIdx.x & 7, loc = blockIdx.x >> 3;
  const int wg = (xcd < r ? xcd * (q + 1) : r * (q + 1) + (xcd - r) * q) + loc;
  const int gy = M >> 8;
  const int m0 = (wg % gy) << 8, n0 = (wg / gy) << 8;

  const int c8 = tid & 7;
  auto stg = [&](char* dst, const bf16* src0, int base0, int half, int ktc) {
#pragma unroll
    for (int i = 0; i < 2; ++i) {
      int hr = i * 64 + (tid >> 3);
      const bf16* s = src0 + (size_t)(base0 + half * 128 + hr) * K + ((size_t)ktc << 6)
                    + ((c8 ^ (hr & 7)) << 3);
      gll16(s, dst + (i * 512 + tid) * 16);
    }
  };
  auto rdf = [&](const char* hbase, int rloc, int ks) -> bf16x8 {
    return *(const bf16x8*)(hbase + rloc * 128 + (((ks << 6) + (lg << 4)) ^ ((rloc & 7) << 4)));
  };

  f32x4 acc[8][4] = {};
  bf16x8 af[4][2], b0f[2][2], b1f[2][2];

  // prologue: A0(0) B0(0) B1(0) A1(0) A0(1) B0(1)  [12 loads; vmcnt(8) => A0(0),B0(0) landed]
  stg(SA[0][0], A, m0, 0, 0);
  stg(SB[0][0], BT, n0, 0, 0);
  stg(SB[0][1], BT, n0, 1, 0);
  stg(SA[0][1], A, m0, 1, 0);
  stg(SA[1][0], A, m0, 0, 1);
  stg(SB[1][0], BT, n0, 0, 1);
  asm volatile("s_waitcnt vmcnt(8)" ::: "memory");
  __builtin_amdgcn_s_barrier();

  for (int kt = 0; kt < nk; ++kt) {
    const int cur = kt & 1;
    const char* hA0 = SA[cur][0]; const char* hA1 = SA[cur][1];
    const char* hB0 = SB[cur][0]; const char* hB1 = SB[cur][1];
    const int tn  = (kt + 1 < nk) ? kt + 1 : nk - 1;
    const int tn2 = (kt + 2 < nk) ? kt + 2 : nk - 1;

    // ---- ph0: quadrant (mi 0-3) x (ni 0-1) ----
    stg(SB[(kt + 1) & 1][1], BT, n0, 1, tn);        // B1(t+1)
    asm volatile("s_waitcnt vmcnt(8)" ::: "memory"); // guard B1(t)
#pragma unroll
    for (int i = 0; i < 4; ++i) {
      int rl = i * 32 + wm * 16 + lr;
#pragma unroll
      for (int ks = 0; ks < 2; ++ks) af[i][ks] = rdf(hA0, rl, ks);
    }
#pragma unroll
    for (int j = 0; j < 2; ++j) {
      int rl = j * 64 + wn * 16 + lr;
#pragma unroll
      for (int ks = 0; ks < 2; ++ks) b0f[j][ks] = rdf(hB0, rl, ks);
    }
    __builtin_amdgcn_s_barrier();
    __builtin_amdgcn_s_setprio(1);
#pragma unroll
    for (int i = 0; i < 4; ++i)
#pragma unroll
      for (int j = 0; j < 2; ++j)
#pragma unroll
        for (int ks = 0; ks < 2; ++ks)
          acc[i][j] = mfma16(af[i][ks], b0f[j][ks], acc[i][j]);
    __builtin_amdgcn_s_setprio(0);

    // ---- ph1: (mi 0-3) x (ni 2-3) ----
    stg(SA[(kt + 1) & 1][1], A, m0, 1, tn);         // A1(t+1)
    asm volatile("s_waitcnt vmcnt(8)" ::: "memory"); // guard A1(t)
#pragma unroll
    for (int j = 0; j < 2; ++j) {
      int rl = j * 64 + wn * 16 + lr;
#pragma unroll
      for (int ks = 0; ks < 2; ++ks) b1f[j][ks] = rdf(hB1, rl, ks);
    }
    __builtin_amdgcn_s_barrier();
    __builtin_amdgcn_s_setprio(1);
#pragma unroll
    for (int i = 0; i < 4; ++i)
#pragma unroll
      for (int j = 0; j < 2; ++j)
#pragma unroll
        for (int ks = 0; ks < 2; ++ks)
          acc[i][2 + j] = mfma16(af[i][ks], b1f[j][ks], acc[i][2 + j]);
    __builtin_amdgcn_s_setprio(0);

    // ---- ph2: (mi 4-7) x (ni 0-1) ----
    stg(SA[cur][0], A, m0, 0, tn2);                 // A0(t+2) into freed slot
#pragma unroll
    for (int i = 0; i < 4; ++i) {
      int rl = i * 32 + wm * 16 + lr;
#pragma unroll
      for (int ks = 0; ks < 2; ++ks) af[i][ks] = rdf(hA1, rl, ks);
    }
    __builtin_amdgcn_s_barrier();
    __builtin_amdgcn_s_setprio(1);
#pragma unroll
    for (int i = 0; i < 4; ++i)
#pragma unroll
      for (int j = 0; j < 2; ++j)
#pragma unroll
        for (int ks = 0; ks < 2; ++ks)
          acc[4 + i][j] = mfma16(af[i][ks], b0f[j][ks], acc[4 + i][j]);
    __builtin_amdgcn_s_setprio(0);

    // ---- ph3: (mi 4-7) x (ni 2-3) ----
    stg(SB[cur][0], BT, n0, 0, tn2);                // B0(t+2) into freed slot
    asm volatile("s_waitcnt vmcnt(8)" ::: "memory"); // guard A0(t+1),B0(t+1)
    __builtin_amdgcn_s_barrier();
    __builtin_amdgcn_s_setprio(1);
#pragma unroll
    for (int i = 0; i < 4; ++i)
#pragma unroll
      for (int j = 0; j < 2; ++j)
#pragma unroll
        for (int ks = 0; ks < 2; ++ks)
          acc[4 + i][2 + j] = mfma16(af[i][ks], b1f[j][ks], acc[4 + i][2 + j]);
    __builtin_amdgcn_s_setprio(0);
  }

  float* of = (float*)Cout;
  bf16*  ob = (bf16*)Cout;
#pragma unroll
  for (int ni = 0; ni < 4; ++ni) {
    int gn = n0 + (ni >> 1) * 128 + (ni & 1) * 64 + wn * 16 + lr;
    float bv = bias[gn];
#pragma unroll
    for (int mi = 0; mi < 8; ++mi) {
      int gmb = m0 + (mi >> 2) * 128 + (mi & 3) * 32 + wm * 16 + lg * 4;
#pragma unroll
      for (int rr = 0; rr < 4; ++rr) {
        size_t idx = (size_t)(gmb + rr) * N + gn;
        float v = acc[mi][ni][rr] + bv;
        if (EPI == 0) ob[idx] = (bf16)v;
        else if (EPI == 1) of[idx] += v;
        else {
          float ge = 0.5f * v * (1.f + erff(v * 0.70710678f));
          ob[idx] = (bf16)ge;
        }
      }
    }
  }
}

// ---------------- fused flash attention v2 (D=64, H=16) ----------------
template <bool CAUSAL>
__global__ __launch_bounds__(256)
void k_attn2(const bf16* __restrict__ Qb, int ldq, int qcol0,
             const bf16* __restrict__ Kb, int kcol0,
             const bf16* __restrict__ Vb, int vcol0,
             int ldkv, int qlen, int kvlen,
             bf16* __restrict__ Ob, int ldo, float scale) {
  const int tid = threadIdx.x;
  const int lane = tid & 63;
  const int w = tid >> 6;
  const int lr = lane & 15, lg = lane >> 4;

  int id = blockIdx.x;
  int h, b, qt;
  if (CAUSAL) {
    int low = id & 255;
    h = low & 15; b = (low >> 4) & 1;
    int q3 = low >> 5;
    qt = (id >> 8) ? (8 + q3) : (7 - q3);
  } else {
    h = id & 15; b = (id >> 4) & 1; qt = id >> 5;
  }

  const int qbase = qt * 128;
  const int kvbase = b * kvlen;
  const int nkv = CAUSAL ? (2 * qt + 2) : (kvlen >> 6);
  const int mask_from = CAUSAL ? (nkv - 2) : 0x7fffffff;

  bf16x8 qf[2][2];
#pragma unroll
  for (int g = 0; g < 2; ++g)
#pragma unroll
    for (int kk = 0; kk < 2; ++kk)
      qf[g][kk] = *(const bf16x8*)(Qb + (size_t)(b * qlen + qbase + w * 32 + g * 16 + lr) * ldq
                                   + qcol0 + h * 64 + kk * 32 + lg * 8);

  __shared__ __align__(16) char Klds[2][8192];
  __shared__ __align__(16) bf16 VT[2][64][68];

  f32x4 o[2][4] = {};
  float mrun[2] = {-3.0e38f, -3.0e38f};
  float lsum[2] = {0.f, 0.f};

  bf16x8 vr0, vr1;
  const int vkv = lane;
  const int vd0 = (tid >> 6) * 16;
  const bf16* Vbase = Vb + vcol0 + h * 64 + vd0;

  auto stageK = [&](int buf, int kvt) {
#pragma unroll
    for (int t = 0; t < 2; ++t) {
      int r = t * 32 + (tid >> 3);
      int pb = (tid & 7) * 16;
      const char* gs = (const char*)(Kb + (size_t)(kvbase + kvt * 64 + r) * ldkv + kcol0 + h * 64)
                       + (pb ^ ((r & 7) << 4));
      gll16(gs, &Klds[buf][t * 4096 + tid * 16]);
    }
  };
  auto loadV = [&](int kvt) {
    const bf16* vp = Vbase + (size_t)(kvbase + kvt * 64 + vkv) * ldkv;
    vr0 = *(const bf16x8*)vp;
    vr1 = *(const bf16x8*)(vp + 8);
  };
  auto writeV = [&](int buf) {
#pragma unroll
    for (int i = 0; i < 8; ++i) VT[buf][vd0 + i][vkv] = vr0[i];
#pragma unroll
    for (int i = 0; i < 8; ++i) VT[buf][vd0 + 8 + i][vkv] = vr1[i];
  };

  stageK(0, 0);
  loadV(0);
  writeV(0);
  __syncthreads();

  int cur = 0;
  for (int kvt = 0; kvt < nkv; ++kvt) {
    if (kvt + 1 < nkv) { stageK(cur ^ 1, kvt + 1); loadV(kvt + 1); }

    f32x4 s[2][4] = {};
#pragma unroll
    for (int sub = 0; sub < 4; ++sub) {
      int row = sub * 16 + lr;
#pragma unroll
      for (int kk = 0; kk < 2; ++kk) {
        bf16x8 kf = *(const bf16x8*)&Klds[cur][(row << 7) + ((kk * 64 + lg * 16) ^ ((row & 7) << 4))];
        s[0][sub] = mfma16(kf, qf[0][kk], s[0][sub]);
        s[1][sub] = mfma16(kf, qf[1][kk], s[1][sub]);
      }
    }

    const bool domask = CAUSAL && (kvt >= mask_from);
    bf16x8 pa[2][2];
#pragma unroll
    for (int g = 0; g < 2; ++g) {
      const int qg = qbase + w * 32 + g * 16 + lr;
      float pmax = -3.0e38f;
#pragma unroll
      for (int sub = 0; sub < 4; ++sub)
#pragma unroll
        for (int j = 0; j < 4; ++j) {
          float v = s[g][sub][j] * scale;
          if (domask) {
            int kvg = kvt * 64 + sub * 16 + lg * 4 + j;
            if (kvg > qg) v = -3.0e38f;
          }
          s[g][sub][j] = v;
          pmax = fmaxf(pmax, v);
        }
      pmax = fmaxf(pmax, __shfl_xor(pmax, 16, 64));
      pmax = fmaxf(pmax, __shfl_xor(pmax, 32, 64));
      float mnew = mrun[g];
      if (__any(pmax - mrun[g] > 8.f)) {
        mnew = fmaxf(mrun[g], pmax);
        float alpha = __expf(mrun[g] - mnew);
        lsum[g] *= alpha;
        float al[4];
#pragma unroll
        for (int j = 0; j < 4; ++j) {
          int src = (lane & 48) | (lg * 4 + j);
          al[j] = __int_as_float(__builtin_amdgcn_ds_bpermute(src << 2, __float_as_int(alpha)));
        }
#pragma unroll
        for (int dt = 0; dt < 4; ++dt)
#pragma unroll
          for (int j = 0; j < 4; ++j) o[g][dt][j] *= al[j];
      }
      float psum = 0.f;
#pragma unroll
      for (int sub = 0; sub < 4; ++sub)
#pragma unroll
        for (int j = 0; j < 4; ++j) {
          float p = __expf(s[g][sub][j] - mnew);
          s[g][sub][j] = p;
          psum += p;
        }
      psum += __shfl_xor(psum, 16, 64);
      psum += __shfl_xor(psum, 32, 64);
      lsum[g] += psum;
      mrun[g] = mnew;
#pragma unroll
      for (int sp = 0; sp < 2; ++sp) {
#pragma unroll
        for (int j = 0; j < 4; ++j) {
          pa[g][sp][j]     = (bf16)s[g][2 * sp][j];
          pa[g][sp][4 + j] = (bf16)s[g][2 * sp + 1][j];
        }
      }
    }

#pragma unroll
    for (int sp = 0; sp < 2; ++sp) {
#pragma unroll
      for (int dt = 0; dt < 4; ++dt) {
        int d = dt * 16 + lr;
        bf16x4 va  = *(const bf16x4*)&VT[cur][d][sp * 32 + lg * 4];
        bf16x4 vb2 = *(const bf16x4*)&VT[cur][d][sp * 32 + 16 + lg * 4];
        bf16x8 vf = __builtin_shufflevector(va, vb2, 0, 1, 2, 3, 4, 5, 6, 7);
        o[0][dt] = mfma16(pa[0][sp], vf, o[0][dt]);
        o[1][dt] = mfma16(pa[1][sp], vf, o[1][dt]);
      }
    }

    if (kvt + 1 < nkv) writeV(cur ^ 1);
    __syncthreads();
    cur ^= 1;
  }

#pragma unroll
  for (int g = 0; g < 2; ++g) {
    float il[4];
#pragma unroll
    for (int j = 0; j < 4; ++j) {
      int src = (lane & 48) | (lg * 4 + j);
      float ls = __int_as_float(__builtin_amdgcn_ds_bpermute(src << 2, __float_as_int(lsum[g])));
      il[j] = 1.0f / ls;
    }
#pragma unroll
    for (int dt = 0; dt < 4; ++dt)
#pragma unroll
      for (int j = 0; j < 4; ++j) {
        int gq = b * qlen + qbase + w * 32 + g * 16 + lg * 4 + j;
        Ob[(size_t)gq * ldo + h * 64 + dt * 16 + lr] = (bf16)(o[g][dt][j] * il[j]);
      }
  }
}

// ---------------- host orchestration ----------------
extern "C" void kernel_launch(void* const* d_in, const int* in_sizes, int n_in,
                              void* d_out, int out_size, void* d_ws, size_t ws_size,
                              hipStream_t stream) {
  (void)in_sizes; (void)n_in; (void)out_size; (void)ws_size;
  const float* x        = (const float*)d_in[0];
  const float* plan     = (const float*)d_in[1];
  const float* ln1_g    = (const float*)d_in[2];
  const float* ln1_b    = (const float*)d_in[3];
  const float* c_attn_w = (const float*)d_in[4];
  const float* c_attn_b = (const float*)d_in[5];
  const float* aproj_w  = (const float*)d_in[6];
  const float* aproj_b  = (const float*)d_in[7];
  const float* ln2_g    = (const float*)d_in[8];
  const float* ln2_b    = (const float*)d_in[9];
  const float* q_w      = (const float*)d_in[10];
  const float* q_b      = (const float*)d_in[11];
  const float* k_w      = (const float*)d_in[12];
  const float* k_b      = (const float*)d_in[13];
  const float* v_w      = (const float*)d_in[14];
  const float* v_b      = (const float*)d_in[15];
  const float* ca_w     = (const float*)d_in[16];
  const float* ca_b     = (const float*)d_in[17];
  const float* ln3_g    = (const float*)d_in[18];
  const float* ln3_b    = (const float*)d_in[19];
  const float* fc_w     = (const float*)d_in[20];
  const float* fc_b     = (const float*)d_in[21];
  const float* mp_w     = (const float*)d_in[22];
  const float* mp_b     = (const float*)d_in[23];

  char* ws = (char*)d_ws;
  bf16*  wbuf   = (bf16*)(ws);                        // 8 MiB rotating W^T
  bf16*  lnb    = (bf16*)(ws + (8ull << 20));         // 8 MiB LN output
  bf16*  planb  = (bf16*)(ws + (16ull << 20));        // 2 MiB plan bf16
  bf16*  yb     = (bf16*)(ws + (18ull << 20));        // 8 MiB attn output
  char*  rega   = ws + (26ull << 20);                 // 32 MiB region (qkv | qx+kv | hmid)
  float* biaskv = (float*)(ws + (58ull << 20));       // 8 KiB
  bf16* qkv  = (bf16*)rega;
  bf16* qx   = (bf16*)rega;
  bf16* kvc  = (bf16*)(rega + (8ull << 20));
  bf16* hmid = (bf16*)rega;
  float* xw = (float*)d_out;   // running residual stream (fp32)

  dim3 wtb(32, 8);

  k_copy_f32<<<4096, 256, 0, stream>>>(x, xw, 1048576);
  k_conv_bf16<<<1024, 256, 0, stream>>>(plan, planb, 262144);
  k_concat2<<<8, 256, 0, stream>>>(k_b, v_b, biaskv, 1024);

  // ----- self-attention -----
  k_ln<<<4096, 256, 0, stream>>>(xw, ln1_g, ln1_b, lnb);
  k_wt<<<dim3(96, 32), wtb, 0, stream>>>(c_attn_w, wbuf, 1024, 3072);
  k_gemm8<0><<<192, 512, 0, stream>>>(lnb, wbuf, c_attn_b, qkv, 4096, 3072, 1024);
  k_attn2<true><<<512, 256, 0, stream>>>(qkv, 3072, 0, qkv, 1024, qkv, 2048,
                                         3072, 2048, 2048, yb, 1024, 0.125f);
  k_wt<<<dim3(32, 32), wtb, 0, stream>>>(aproj_w, wbuf, 1024, 1024);
  k_gemm<1><<<dim3(8, 32), 256, 0, stream>>>(yb, wbuf, aproj_b, xw, 4096, 1024, 1024);

  // ----- cross-attention -----
  k_ln<<<4096, 256, 0, stream>>>(xw, ln2_g, ln2_b, lnb);
  k_wt<<<dim3(32, 32), wtb, 0, stream>>>(q_w, wbuf, 1024, 1024);
  k_gemm<0><<<dim3(8, 32), 256, 0, stream>>>(lnb, wbuf, q_b, qx, 4096, 1024, 1024);
  k_wt<<<dim3(32, 32), wtb, 0, stream>>>(k_w, wbuf, 1024, 1024);
  k_wt<<<dim3(32, 32), wtb, 0, stream>>>(v_w, wbuf + 1024 * 1024, 1024, 1024);
  k_gemm<0><<<dim3(16, 8), 256, 0, stream>>>(planb, wbuf, biaskv, kvc, 1024, 2048, 1024);
  k_attn2<false><<<512, 256, 0, stream>>>(qx, 1024, 0, kvc, 0, kvc, 1024,
                                          2048, 2048, 512, yb, 1024, 0.125f);
  k_wt<<<dim3(32, 32), wtb, 0, stream>>>(ca_w, wbuf, 1024, 1024);
  k_gemm<1><<<dim3(8, 32), 256, 0, stream>>>(yb, wbuf, ca_b, xw, 4096, 1024, 1024);

  // ----- MLP -----
  k_ln<<<4096, 256, 0, stream>>>(xw, ln3_g, ln3_b, lnb);
  k_wt<<<dim3(128, 32), wtb, 0, stream>>>(fc_w, wbuf, 1024, 4096);
  k_gemm8<2><<<256, 512, 0, stream>>>(lnb, wbuf, fc_b, hmid, 4096, 4096, 1024);
  k_wt<<<dim3(32, 128), wtb, 0, stream>>>(mp_w, wbuf, 4096, 1024);
  k_gemm<1><<<dim3(8, 32), 256, 0, stream>>>(hmid, wbuf, mp_b, xw, 4096, 1024, 4096);
}

// Round 4
// 370.284 us; speedup vs baseline: 1.1610x; 1.0988x over previous
//
#include <hip/hip_runtime.h>
#include <stdint.h>

typedef __bf16 bf16;
typedef __bf16 bf16x4 __attribute__((ext_vector_type(4)));
typedef __bf16 bf16x8 __attribute__((ext_vector_type(8)));
typedef float  f32x4  __attribute__((ext_vector_type(4)));

#define DEVI __device__ __forceinline__

DEVI void gll16(const void* g, void* l) {
  __builtin_amdgcn_global_load_lds(
      (const __attribute__((address_space(1))) void*)g,
      (__attribute__((address_space(3))) void*)l,
      16, 0, 0);
}

DEVI f32x4 mfma16(bf16x8 a, bf16x8 b, f32x4 c) {
  return __builtin_amdgcn_mfma_f32_16x16x32_bf16(a, b, c, 0, 0, 0);
}

// ---------------- elementwise ----------------
__global__ void k_copy_f32(const float* __restrict__ in, float* __restrict__ out, int n4) {
  int i = blockIdx.x * 256 + threadIdx.x;
  if (i < n4) ((f32x4*)out)[i] = ((const f32x4*)in)[i];
}

__global__ void k_conv_bf16(const float* __restrict__ in, bf16* __restrict__ out, int n4) {
  int i = blockIdx.x * 256 + threadIdx.x;
  if (i < n4) {
    f32x4 v = ((const f32x4*)in)[i];
    bf16x4 o;
    o[0] = (bf16)v[0]; o[1] = (bf16)v[1]; o[2] = (bf16)v[2]; o[3] = (bf16)v[3];
    ((bf16x4*)out)[i] = o;
  }
}

__global__ void k_concat2(const float* __restrict__ a, const float* __restrict__ b,
                          float* __restrict__ out, int n) {
  int i = blockIdx.x * 256 + threadIdx.x;
  if (i < n) out[i] = a[i];
  else if (i < 2 * n) out[i] = b[i - n];
}

// ------------- weight fp32 [K][N] -> bf16 W^T [N][K] -------------
__global__ void k_wt(const float* __restrict__ W, bf16* __restrict__ WT, int K, int N) {
  __shared__ float t[32][33];
  int bn = blockIdx.x * 32, bk = blockIdx.y * 32;
  int tx = threadIdx.x, ty = threadIdx.y;
#pragma unroll
  for (int i = 0; i < 4; ++i)
    t[ty + i * 8][tx] = W[(size_t)(bk + ty + i * 8) * N + bn + tx];
  __syncthreads();
#pragma unroll
  for (int i = 0; i < 4; ++i)
    WT[(size_t)(bn + ty + i * 8) * K + bk + tx] = (bf16)t[tx][ty + i * 8];
}

// ---------------- layernorm (C=1024) fp32 -> bf16 ----------------
__global__ __launch_bounds__(256)
void k_ln(const float* __restrict__ x, const float* __restrict__ g,
          const float* __restrict__ b, bf16* __restrict__ out) {
  int row = blockIdx.x, tid = threadIdx.x;
  f32x4 v = ((const f32x4*)(x + (size_t)row * 1024))[tid];
  float s = v[0] + v[1] + v[2] + v[3];
  float sq = v[0]*v[0] + v[1]*v[1] + v[2]*v[2] + v[3]*v[3];
#pragma unroll
  for (int m = 1; m < 64; m <<= 1) {
    s  += __shfl_xor(s, m, 64);
    sq += __shfl_xor(sq, m, 64);
  }
  __shared__ float ps[4], psq[4];
  int w = tid >> 6;
  if ((tid & 63) == 0) { ps[w] = s; psq[w] = sq; }
  __syncthreads();
  s  = ps[0] + ps[1] + ps[2] + ps[3];
  sq = psq[0] + psq[1] + psq[2] + psq[3];
  float mean = s * (1.f / 1024.f);
  float rs = rsqrtf(sq * (1.f / 1024.f) - mean * mean + 1e-5f);
  f32x4 gv = ((const f32x4*)g)[tid];
  f32x4 bv = ((const f32x4*)b)[tid];
  bf16x4 o;
#pragma unroll
  for (int i = 0; i < 4; ++i) o[i] = (bf16)((v[i] - mean) * rs * gv[i] + bv[i]);
  ((bf16x4*)(out + (size_t)row * 1024))[tid] = o;
}

// ---------------- GEMM small-tile: BM=64 BN=128 BK=64, 2-phase, 3 blk/CU ----------------
// For M x ~1024 shapes whose 128^2 grids give only 1 block/CU (exposed barrier drain).
// T2 XOR-swizzled LDS (pre-swizzled global source, linear LDS dest); XCD-chunked
// M-fastest ordering for B-panel L2 reuse. Grid 1D = (N/128)*(M/64).
// EPI 0: bf16 out.  EPI 1: fp32 out[idx] += v.  EPI 2: gelu->bf16.
template <int EPI>
__global__ __launch_bounds__(256, 3)
void k_gemm_s(const bf16* __restrict__ A, const bf16* __restrict__ BT,
              const float* __restrict__ bias, void* __restrict__ Cout,
              int M, int N, int K) {
  __shared__ __align__(16) char SA[2][8192];    // 64 rows x 128B
  __shared__ __align__(16) char SB[2][16384];   // 128 rows x 128B
  const int tid = threadIdx.x;
  const int lane = tid & 63;
  const int w = tid >> 6;
  const int wr = w >> 1, wc = w & 1;
  const int lr = lane & 15, lg = lane >> 4;
  const int nk = K >> 6;

  // bijective XCD swizzle (m204), M-fastest so an XCD chunk shares one B-panel
  const int nwg = gridDim.x;
  const int q = nwg >> 3, r = nwg & 7;
  const int xcd = blockIdx.x & 7, loc = blockIdx.x >> 3;
  const int wg = (xcd < r ? xcd * (q + 1) : r * (q + 1) + (xcd - r) * q) + loc;
  const int gy = M >> 6;
  const int m0 = (wg % gy) << 6, n0 = (wg / gy) << 7;

  const int c8 = tid & 7;
  const int hrb = tid >> 3;
  auto stgA = [&](int buf, int ktc) {
#pragma unroll
    for (int i = 0; i < 2; ++i) {
      int hr = i * 32 + hrb;
      const bf16* s = A + (size_t)(m0 + hr) * K + ((size_t)ktc << 6) + ((c8 ^ (hr & 7)) << 3);
      gll16(s, &SA[buf][(i * 256 + tid) * 16]);
    }
  };
  auto stgB = [&](int buf, int ktc) {
#pragma unroll
    for (int i = 0; i < 4; ++i) {
      int hr = i * 32 + hrb;
      const bf16* s = BT + (size_t)(n0 + hr) * K + ((size_t)ktc << 6) + ((c8 ^ (hr & 7)) << 3);
      gll16(s, &SB[buf][(i * 256 + tid) * 16]);
    }
  };
  auto rdf = [&](const char* base, int rloc, int ks) -> bf16x8 {
    return *(const bf16x8*)(base + rloc * 128 + (((ks << 6) + (lg << 4)) ^ ((rloc & 7) << 4)));
  };

  f32x4 acc[2][4] = {};

  stgA(0, 0); stgB(0, 0);
  __syncthreads();
  for (int kt = 0; kt < nk; ++kt) {
    const int cur = kt & 1;
    if (kt + 1 < nk) { stgA(cur ^ 1, kt + 1); stgB(cur ^ 1, kt + 1); }
    bf16x8 af[2][2], bfr[4][2];
#pragma unroll
    for (int i = 0; i < 2; ++i)
#pragma unroll
      for (int ks = 0; ks < 2; ++ks)
        af[i][ks] = rdf(SA[cur], wr * 32 + i * 16 + lr, ks);
#pragma unroll
    for (int j = 0; j < 4; ++j)
#pragma unroll
      for (int ks = 0; ks < 2; ++ks)
        bfr[j][ks] = rdf(SB[cur], wc * 64 + j * 16 + lr, ks);
#pragma unroll
    for (int i = 0; i < 2; ++i)
#pragma unroll
      for (int j = 0; j < 4; ++j)
#pragma unroll
        for (int ks = 0; ks < 2; ++ks)
          acc[i][j] = mfma16(af[i][ks], bfr[j][ks], acc[i][j]);
    __syncthreads();
  }

  float* of = (float*)Cout;
  bf16*  ob = (bf16*)Cout;
#pragma unroll
  for (int j = 0; j < 4; ++j) {
    int gn = n0 + wc * 64 + j * 16 + lr;
    float bv = bias[gn];
#pragma unroll
    for (int i = 0; i < 2; ++i) {
      int gmb = m0 + wr * 32 + i * 16 + lg * 4;
#pragma unroll
      for (int rr = 0; rr < 4; ++rr) {
        size_t idx = (size_t)(gmb + rr) * N + gn;
        float v = acc[i][j][rr] + bv;
        if (EPI == 0) ob[idx] = (bf16)v;
        else if (EPI == 1) of[idx] += v;
        else {
          float ge = 0.5f * v * (1.f + erff(v * 0.70710678f));
          ob[idx] = (bf16)ge;
        }
      }
    }
  }
}

// ---------------- GEMM 256x256 8-phase counted-vmcnt (T2+T3+T4+T5) ----------------
template <int EPI>
__global__ __launch_bounds__(512, 2)
void k_gemm8(const bf16* __restrict__ A, const bf16* __restrict__ BT,
             const float* __restrict__ bias, void* __restrict__ Cout,
             int M, int N, int K) {
  __shared__ __align__(16) char SA[2][2][16384];
  __shared__ __align__(16) char SB[2][2][16384];
  const int tid = threadIdx.x;
  const int lane = tid & 63;
  const int w = tid >> 6;
  const int wm = w >> 2, wn = w & 3;
  const int lr = lane & 15, lg = lane >> 4;
  const int nk = K >> 6;

  const int nwg = gridDim.x;
  const int q = nwg >> 3, r = nwg & 7;
  const int xcd = blockIdx.x & 7, loc = blockIdx.x >> 3;
  const int wg = (xcd < r ? xcd * (q + 1) : r * (q + 1) + (xcd - r) * q) + loc;
  const int gy = M >> 8;
  const int m0 = (wg % gy) << 8, n0 = (wg / gy) << 8;

  const int c8 = tid & 7;
  auto stg = [&](char* dst, const bf16* src0, int base0, int half, int ktc) {
#pragma unroll
    for (int i = 0; i < 2; ++i) {
      int hr = i * 64 + (tid >> 3);
      const bf16* s = src0 + (size_t)(base0 + half * 128 + hr) * K + ((size_t)ktc << 6)
                    + ((c8 ^ (hr & 7)) << 3);
      gll16(s, dst + (i * 512 + tid) * 16);
    }
  };
  auto rdf = [&](const char* hbase, int rloc, int ks) -> bf16x8 {
    return *(const bf16x8*)(hbase + rloc * 128 + (((ks << 6) + (lg << 4)) ^ ((rloc & 7) << 4)));
  };

  f32x4 acc[8][4] = {};
  bf16x8 af[4][2], b0f[2][2], b1f[2][2];

  stg(SA[0][0], A, m0, 0, 0);
  stg(SB[0][0], BT, n0, 0, 0);
  stg(SB[0][1], BT, n0, 1, 0);
  stg(SA[0][1], A, m0, 1, 0);
  stg(SA[1][0], A, m0, 0, 1);
  stg(SB[1][0], BT, n0, 0, 1);
  asm volatile("s_waitcnt vmcnt(8)" ::: "memory");
  __builtin_amdgcn_s_barrier();

  for (int kt = 0; kt < nk; ++kt) {
    const int cur = kt & 1;
    const char* hA0 = SA[cur][0]; const char* hA1 = SA[cur][1];
    const char* hB0 = SB[cur][0]; const char* hB1 = SB[cur][1];
    const int tn  = (kt + 1 < nk) ? kt + 1 : nk - 1;
    const int tn2 = (kt + 2 < nk) ? kt + 2 : nk - 1;

    stg(SB[(kt + 1) & 1][1], BT, n0, 1, tn);
    asm volatile("s_waitcnt vmcnt(8)" ::: "memory");
#pragma unroll
    for (int i = 0; i < 4; ++i) {
      int rl = i * 32 + wm * 16 + lr;
#pragma unroll
      for (int ks = 0; ks < 2; ++ks) af[i][ks] = rdf(hA0, rl, ks);
    }
#pragma unroll
    for (int j = 0; j < 2; ++j) {
      int rl = j * 64 + wn * 16 + lr;
#pragma unroll
      for (int ks = 0; ks < 2; ++ks) b0f[j][ks] = rdf(hB0, rl, ks);
    }
    __builtin_amdgcn_s_barrier();
    __builtin_amdgcn_s_setprio(1);
#pragma unroll
    for (int i = 0; i < 4; ++i)
#pragma unroll
      for (int j = 0; j < 2; ++j)
#pragma unroll
        for (int ks = 0; ks < 2; ++ks)
          acc[i][j] = mfma16(af[i][ks], b0f[j][ks], acc[i][j]);
    __builtin_amdgcn_s_setprio(0);

    stg(SA[(kt + 1) & 1][1], A, m0, 1, tn);
    asm volatile("s_waitcnt vmcnt(8)" ::: "memory");
#pragma unroll
    for (int j = 0; j < 2; ++j) {
      int rl = j * 64 + wn * 16 + lr;
#pragma unroll
      for (int ks = 0; ks < 2; ++ks) b1f[j][ks] = rdf(hB1, rl, ks);
    }
    __builtin_amdgcn_s_barrier();
    __builtin_amdgcn_s_setprio(1);
#pragma unroll
    for (int i = 0; i < 4; ++i)
#pragma unroll
      for (int j = 0; j < 2; ++j)
#pragma unroll
        for (int ks = 0; ks < 2; ++ks)
          acc[i][2 + j] = mfma16(af[i][ks], b1f[j][ks], acc[i][2 + j]);
    __builtin_amdgcn_s_setprio(0);

    stg(SA[cur][0], A, m0, 0, tn2);
#pragma unroll
    for (int i = 0; i < 4; ++i) {
      int rl = i * 32 + wm * 16 + lr;
#pragma unroll
      for (int ks = 0; ks < 2; ++ks) af[i][ks] = rdf(hA1, rl, ks);
    }
    __builtin_amdgcn_s_barrier();
    __builtin_amdgcn_s_setprio(1);
#pragma unroll
    for (int i = 0; i < 4; ++i)
#pragma unroll
      for (int j = 0; j < 2; ++j)
#pragma unroll
        for (int ks = 0; ks < 2; ++ks)
          acc[4 + i][j] = mfma16(af[i][ks], b0f[j][ks], acc[4 + i][j]);
    __builtin_amdgcn_s_setprio(0);

    stg(SB[cur][0], BT, n0, 0, tn2);
    asm volatile("s_waitcnt vmcnt(8)" ::: "memory");
    __builtin_amdgcn_s_barrier();
    __builtin_amdgcn_s_setprio(1);
#pragma unroll
    for (int i = 0; i < 4; ++i)
#pragma unroll
      for (int j = 0; j < 2; ++j)
#pragma unroll
        for (int ks = 0; ks < 2; ++ks)
          acc[4 + i][2 + j] = mfma16(af[i][ks], b1f[j][ks], acc[4 + i][2 + j]);
    __builtin_amdgcn_s_setprio(0);
  }

  float* of = (float*)Cout;
  bf16*  ob = (bf16*)Cout;
#pragma unroll
  for (int ni = 0; ni < 4; ++ni) {
    int gn = n0 + (ni >> 1) * 128 + (ni & 1) * 64 + wn * 16 + lr;
    float bv = bias[gn];
#pragma unroll
    for (int mi = 0; mi < 8; ++mi) {
      int gmb = m0 + (mi >> 2) * 128 + (mi & 3) * 32 + wm * 16 + lg * 4;
#pragma unroll
      for (int rr = 0; rr < 4; ++rr) {
        size_t idx = (size_t)(gmb + rr) * N + gn;
        float v = acc[mi][ni][rr] + bv;
        if (EPI == 0) ob[idx] = (bf16)v;
        else if (EPI == 1) of[idx] += v;
        else {
          float ge = 0.5f * v * (1.f + erff(v * 0.70710678f));
          ob[idx] = (bf16)ge;
        }
      }
    }
  }
}

// ---------------- fused flash attention v2 (D=64, H=16) ----------------
template <bool CAUSAL>
__global__ __launch_bounds__(256)
void k_attn2(const bf16* __restrict__ Qb, int ldq, int qcol0,
             const bf16* __restrict__ Kb, int kcol0,
             const bf16* __restrict__ Vb, int vcol0,
             int ldkv, int qlen, int kvlen,
             bf16* __restrict__ Ob, int ldo, float scale) {
  const int tid = threadIdx.x;
  const int lane = tid & 63;
  const int w = tid >> 6;
  const int lr = lane & 15, lg = lane >> 4;

  int id = blockIdx.x;
  int h, b, qt;
  if (CAUSAL) {
    int low = id & 255;
    h = low & 15; b = (low >> 4) & 1;
    int q3 = low >> 5;
    qt = (id >> 8) ? (8 + q3) : (7 - q3);
  } else {
    h = id & 15; b = (id >> 4) & 1; qt = id >> 5;
  }

  const int qbase = qt * 128;
  const int kvbase = b * kvlen;
  const int nkv = CAUSAL ? (2 * qt + 2) : (kvlen >> 6);
  const int mask_from = CAUSAL ? (nkv - 2) : 0x7fffffff;

  bf16x8 qf[2][2];
#pragma unroll
  for (int g = 0; g < 2; ++g)
#pragma unroll
    for (int kk = 0; kk < 2; ++kk)
      qf[g][kk] = *(const bf16x8*)(Qb + (size_t)(b * qlen + qbase + w * 32 + g * 16 + lr) * ldq
                                   + qcol0 + h * 64 + kk * 32 + lg * 8);

  __shared__ __align__(16) char Klds[2][8192];
  __shared__ __align__(16) bf16 VT[2][64][68];

  f32x4 o[2][4] = {};
  float mrun[2] = {-3.0e38f, -3.0e38f};
  float lsum[2] = {0.f, 0.f};

  bf16x8 vr0, vr1;
  const int vkv = lane;
  const int vd0 = (tid >> 6) * 16;
  const bf16* Vbase = Vb + vcol0 + h * 64 + vd0;

  auto stageK = [&](int buf, int kvt) {
#pragma unroll
    for (int t = 0; t < 2; ++t) {
      int r = t * 32 + (tid >> 3);
      int pb = (tid & 7) * 16;
      const char* gs = (const char*)(Kb + (size_t)(kvbase + kvt * 64 + r) * ldkv + kcol0 + h * 64)
                       + (pb ^ ((r & 7) << 4));
      gll16(gs, &Klds[buf][t * 4096 + tid * 16]);
    }
  };
  auto loadV = [&](int kvt) {
    const bf16* vp = Vbase + (size_t)(kvbase + kvt * 64 + vkv) * ldkv;
    vr0 = *(const bf16x8*)vp;
    vr1 = *(const bf16x8*)(vp + 8);
  };
  auto writeV = [&](int buf) {
#pragma unroll
    for (int i = 0; i < 8; ++i) VT[buf][vd0 + i][vkv] = vr0[i];
#pragma unroll
    for (int i = 0; i < 8; ++i) VT[buf][vd0 + 8 + i][vkv] = vr1[i];
  };

  stageK(0, 0);
  loadV(0);
  writeV(0);
  __syncthreads();

  int cur = 0;
  for (int kvt = 0; kvt < nkv; ++kvt) {
    if (kvt + 1 < nkv) { stageK(cur ^ 1, kvt + 1); loadV(kvt + 1); }

    f32x4 s[2][4] = {};
#pragma unroll
    for (int sub = 0; sub < 4; ++sub) {
      int row = sub * 16 + lr;
#pragma unroll
      for (int kk = 0; kk < 2; ++kk) {
        bf16x8 kf = *(const bf16x8*)&Klds[cur][(row << 7) + ((kk * 64 + lg * 16) ^ ((row & 7) << 4))];
        s[0][sub] = mfma16(kf, qf[0][kk], s[0][sub]);
        s[1][sub] = mfma16(kf, qf[1][kk], s[1][sub]);
      }
    }

    const bool domask = CAUSAL && (kvt >= mask_from);
    bf16x8 pa[2][2];
#pragma unroll
    for (int g = 0; g < 2; ++g) {
      const int qg = qbase + w * 32 + g * 16 + lr;
      float pmax = -3.0e38f;
#pragma unroll
      for (int sub = 0; sub < 4; ++sub)
#pragma unroll
        for (int j = 0; j < 4; ++j) {
          float v = s[g][sub][j] * scale;
          if (domask) {
            int kvg = kvt * 64 + sub * 16 + lg * 4 + j;
            if (kvg > qg) v = -3.0e38f;
          }
          s[g][sub][j] = v;
          pmax = fmaxf(pmax, v);
        }
      pmax = fmaxf(pmax, __shfl_xor(pmax, 16, 64));
      pmax = fmaxf(pmax, __shfl_xor(pmax, 32, 64));
      float mnew = mrun[g];
      if (__any(pmax - mrun[g] > 8.f)) {
        mnew = fmaxf(mrun[g], pmax);
        float alpha = __expf(mrun[g] - mnew);
        lsum[g] *= alpha;
        float al[4];
#pragma unroll
        for (int j = 0; j < 4; ++j) {
          int src = (lane & 48) | (lg * 4 + j);
          al[j] = __int_as_float(__builtin_amdgcn_ds_bpermute(src << 2, __float_as_int(alpha)));
        }
#pragma unroll
        for (int dt = 0; dt < 4; ++dt)
#pragma unroll
          for (int j = 0; j < 4; ++j) o[g][dt][j] *= al[j];
      }
      float psum = 0.f;
#pragma unroll
      for (int sub = 0; sub < 4; ++sub)
#pragma unroll
        for (int j = 0; j < 4; ++j) {
          float p = __expf(s[g][sub][j] - mnew);
          s[g][sub][j] = p;
          psum += p;
        }
      psum += __shfl_xor(psum, 16, 64);
      psum += __shfl_xor(psum, 32, 64);
      lsum[g] += psum;
      mrun[g] = mnew;
#pragma unroll
      for (int sp = 0; sp < 2; ++sp) {
#pragma unroll
        for (int j = 0; j < 4; ++j) {
          pa[g][sp][j]     = (bf16)s[g][2 * sp][j];
          pa[g][sp][4 + j] = (bf16)s[g][2 * sp + 1][j];
        }
      }
    }

#pragma unroll
    for (int sp = 0; sp < 2; ++sp) {
#pragma unroll
      for (int dt = 0; dt < 4; ++dt) {
        int d = dt * 16 + lr;
        bf16x4 va  = *(const bf16x4*)&VT[cur][d][sp * 32 + lg * 4];
        bf16x4 vb2 = *(const bf16x4*)&VT[cur][d][sp * 32 + 16 + lg * 4];
        bf16x8 vf = __builtin_shufflevector(va, vb2, 0, 1, 2, 3, 4, 5, 6, 7);
        o[0][dt] = mfma16(pa[0][sp], vf, o[0][dt]);
        o[1][dt] = mfma16(pa[1][sp], vf, o[1][dt]);
      }
    }

    if (kvt + 1 < nkv) writeV(cur ^ 1);
    __syncthreads();
    cur ^= 1;
  }

#pragma unroll
  for (int g = 0; g < 2; ++g) {
    float il[4];
#pragma unroll
    for (int j = 0; j < 4; ++j) {
      int src = (lane & 48) | (lg * 4 + j);
      float ls = __int_as_float(__builtin_amdgcn_ds_bpermute(src << 2, __float_as_int(lsum[g])));
      il[j] = 1.0f / ls;
    }
#pragma unroll
    for (int dt = 0; dt < 4; ++dt)
#pragma unroll
      for (int j = 0; j < 4; ++j) {
        int gq = b * qlen + qbase + w * 32 + g * 16 + lg * 4 + j;
        Ob[(size_t)gq * ldo + h * 64 + dt * 16 + lr] = (bf16)(o[g][dt][j] * il[j]);
      }
  }
}

// ---------------- host orchestration ----------------
extern "C" void kernel_launch(void* const* d_in, const int* in_sizes, int n_in,
                              void* d_out, int out_size, void* d_ws, size_t ws_size,
                              hipStream_t stream) {
  (void)in_sizes; (void)n_in; (void)out_size; (void)ws_size;
  const float* x        = (const float*)d_in[0];
  const float* plan     = (const float*)d_in[1];
  const float* ln1_g    = (const float*)d_in[2];
  const float* ln1_b    = (const float*)d_in[3];
  const float* c_attn_w = (const float*)d_in[4];
  const float* c_attn_b = (const float*)d_in[5];
  const float* aproj_w  = (const float*)d_in[6];
  const float* aproj_b  = (const float*)d_in[7];
  const float* ln2_g    = (const float*)d_in[8];
  const float* ln2_b    = (const float*)d_in[9];
  const float* q_w      = (const float*)d_in[10];
  const float* q_b      = (const float*)d_in[11];
  const float* k_w      = (const float*)d_in[12];
  const float* k_b      = (const float*)d_in[13];
  const float* v_w      = (const float*)d_in[14];
  const float* v_b      = (const float*)d_in[15];
  const float* ca_w     = (const float*)d_in[16];
  const float* ca_b     = (const float*)d_in[17];
  const float* ln3_g    = (const float*)d_in[18];
  const float* ln3_b    = (const float*)d_in[19];
  const float* fc_w     = (const float*)d_in[20];
  const float* fc_b     = (const float*)d_in[21];
  const float* mp_w     = (const float*)d_in[22];
  const float* mp_b     = (const float*)d_in[23];

  char* ws = (char*)d_ws;
  bf16*  wbuf   = (bf16*)(ws);                        // 8 MiB rotating W^T
  bf16*  lnb    = (bf16*)(ws + (8ull << 20));         // 8 MiB LN output
  bf16*  planb  = (bf16*)(ws + (16ull << 20));        // 2 MiB plan bf16
  bf16*  yb     = (bf16*)(ws + (18ull << 20));        // 8 MiB attn output
  char*  rega   = ws + (26ull << 20);                 // 32 MiB region (qkv | qx+kv | hmid)
  float* biaskv = (float*)(ws + (58ull << 20));       // 8 KiB
  bf16* qkv  = (bf16*)rega;
  bf16* qx   = (bf16*)rega;
  bf16* kvc  = (bf16*)(rega + (8ull << 20));
  bf16* hmid = (bf16*)rega;
  float* xw = (float*)d_out;   // running residual stream (fp32)

  dim3 wtb(32, 8);

  k_copy_f32<<<4096, 256, 0, stream>>>(x, xw, 1048576);
  k_conv_bf16<<<1024, 256, 0, stream>>>(plan, planb, 262144);
  k_concat2<<<8, 256, 0, stream>>>(k_b, v_b, biaskv, 1024);

  // ----- self-attention -----
  k_ln<<<4096, 256, 0, stream>>>(xw, ln1_g, ln1_b, lnb);
  k_wt<<<dim3(96, 32), wtb, 0, stream>>>(c_attn_w, wbuf, 1024, 3072);
  k_gemm8<0><<<192, 512, 0, stream>>>(lnb, wbuf, c_attn_b, qkv, 4096, 3072, 1024);
  k_attn2<true><<<512, 256, 0, stream>>>(qkv, 3072, 0, qkv, 1024, qkv, 2048,
                                         3072, 2048, 2048, yb, 1024, 0.125f);
  k_wt<<<dim3(32, 32), wtb, 0, stream>>>(aproj_w, wbuf, 1024, 1024);
  k_gemm_s<1><<<512, 256, 0, stream>>>(yb, wbuf, aproj_b, xw, 4096, 1024, 1024);

  // ----- cross-attention -----
  k_ln<<<4096, 256, 0, stream>>>(xw, ln2_g, ln2_b, lnb);
  k_wt<<<dim3(32, 32), wtb, 0, stream>>>(q_w, wbuf, 1024, 1024);
  k_gemm_s<0><<<512, 256, 0, stream>>>(lnb, wbuf, q_b, qx, 4096, 1024, 1024);
  k_wt<<<dim3(32, 32), wtb, 0, stream>>>(k_w, wbuf, 1024, 1024);
  k_wt<<<dim3(32, 32), wtb, 0, stream>>>(v_w, wbuf + 1024 * 1024, 1024, 1024);
  k_gemm_s<0><<<256, 256, 0, stream>>>(planb, wbuf, biaskv, kvc, 1024, 2048, 1024);
  k_attn2<false><<<512, 256, 0, stream>>>(qx, 1024, 0, kvc, 0, kvc, 1024,
                                          2048, 2048, 512, yb, 1024, 0.125f);
  k_wt<<<dim3(32, 32), wtb, 0, stream>>>(ca_w, wbuf, 1024, 1024);
  k_gemm_s<1><<<512, 256, 0, stream>>>(yb, wbuf, ca_b, xw, 4096, 1024, 1024);

  // ----- MLP -----
  k_ln<<<4096, 256, 0, stream>>>(xw, ln3_g, ln3_b, lnb);
  k_wt<<<dim3(128, 32), wtb, 0, stream>>>(fc_w, wbuf, 1024, 4096);
  k_gemm8<2><<<256, 512, 0, stream>>>(lnb, wbuf, fc_b, hmid, 4096, 4096, 1024);
  k_wt<<<dim3(32, 128), wtb, 0, stream>>>(mp_w, wbuf, 4096, 1024);
  k_gemm_s<1><<<512, 256, 0, stream>>>(hmid, wbuf, mp_b, xw, 4096, 1024, 4096);
}